// Round 1
// baseline (656.098 us; speedup 1.0000x reference)
//
#include <hip/hip_runtime.h>
#include <stdint.h>

// MultiHeadAttention fwd: out = (softmax(QK^T/8) V) Wo^T + bo, also emit attn.
// Round 1: unfused pipeline, one NT bf16-MFMA GEMM template for all matmuls.
// d_out = [out: 4194304 f32][attn: 134217728 f32]
// d_ws  = [W bf16: 4x1M][q bf16][k bf16][vT bf16][ctx bf16]  (40 MB total)

#define DEV __device__ __forceinline__

typedef __attribute__((ext_vector_type(8))) short short8;
typedef __attribute__((ext_vector_type(4))) short short4v;
typedef __attribute__((ext_vector_type(4))) float f32x4;

DEV short f2bf(float f) {  // round-to-nearest-even f32 -> bf16 bits
  uint32_t u = __builtin_bit_cast(uint32_t, f);
  u += 0x7fffu + ((u >> 16) & 1u);
  return (short)(u >> 16);
}

DEV void gload_lds16(const void* g, void* l) {
  __builtin_amdgcn_global_load_lds(
      (const __attribute__((address_space(1))) void*)g,
      (__attribute__((address_space(3))) void*)l,
      16, 0, 0);
}

enum { M_PROJ = 0, M_SCORES = 1, M_PV = 2, M_OUT = 3 };

struct GP {
  const void* A0; const void* A1; const void* A2;  // A sources (f32 or bf16)
  const short* B;                                  // bf16 NT operand [n][k]
  const float* b0; const float* b1; const float* b2;
  void* C;
  int lda, ldb, K;
  long aBS, bBS;   // per-blockIdx.z batch strides (elements)
};

// C[m,n] = sum_k A[m,k]*B[n,k] ; BM=WM*16*AM, BN=WN*16*AN, BK=64, 256 threads.
// LDS tiles XOR-swizzled: byte = (row*128 + 2k) ^ ((row&7)<<4)  (G4 fix).
template<int WM, int WN, int AM, int AN, bool CONVA, int MODE>
__global__ __launch_bounds__(256) void gemm_nt(GP p) {
  constexpr int BM = WM * 16 * AM;
  constexpr int BN = WN * 16 * AN;
  static_assert(WM * WN == 4, "4 waves / 256 threads");
  __shared__ __align__(16) char As[BM * 128];
  __shared__ __align__(16) char Bs[BN * 128];

  const int tid = threadIdx.x;
  const int lane = tid & 63;
  const int z = blockIdx.z;
  const int bm0 = blockIdx.y * BM;
  const int bn0 = blockIdx.x * BN;

  const void* Aroot; const float* bias;
  if constexpr (MODE == M_PROJ) {
    Aroot = (z == 0) ? p.A0 : (z == 1 ? p.A1 : p.A2);
    bias  = (z == 0) ? p.b0 : (z == 1 ? p.b1 : p.b2);
  } else {
    Aroot = p.A0; bias = p.b0;
  }

  f32x4 acc[AM][AN];
#pragma unroll
  for (int m = 0; m < AM; ++m)
#pragma unroll
    for (int n = 0; n < AN; ++n) acc[m][n] = f32x4{0.f, 0.f, 0.f, 0.f};

  const int wave = tid >> 6;
  const int wm = wave / WN;
  const int wn = wave % WN;

  const int nK = p.K >> 6;
  for (int kt = 0; kt < nK; ++kt) {
    // ---- stage A ----
    if constexpr (CONVA) {  // fp32 source, reg-stage + convert, swizzled ds_write
      const float* Af = (const float*)Aroot + (size_t)z * p.aBS +
                        (size_t)bm0 * p.lda + kt * 64;
#pragma unroll
      for (int sw = 0; sw < BM / 16; ++sw) {
        const int r = sw * 16 + (tid >> 4);
        const int s8 = tid & 15;
        const float4 v = *(const float4*)(Af + (size_t)r * p.lda + s8 * 4);
        short4v o;
        o[0] = f2bf(v.x); o[1] = f2bf(v.y); o[2] = f2bf(v.z); o[3] = f2bf(v.w);
        const int boff = (r * 128 + s8 * 8) ^ ((r & 7) << 4);
        *(short4v*)(As + boff) = o;
      }
    } else {  // bf16 source: global_load_lds (linear dest, inverse-swizzled src)
      const short* Ab = (const short*)Aroot + (size_t)z * p.aBS +
                        (size_t)bm0 * p.lda + kt * 64;
#pragma unroll
      for (int sw = 0; sw < BM / 32; ++sw) {
        const int r = sw * 32 + (tid >> 3);
        const int c8 = (tid & 7) ^ (r & 7);
        gload_lds16(Ab + (size_t)r * p.lda + c8 * 8, As + (sw * 256 + tid) * 16);
      }
    }
    // ---- stage B (always bf16) ----
    {
      const short* Bb = p.B + (size_t)z * p.bBS + (size_t)bn0 * p.ldb + kt * 64;
#pragma unroll
      for (int sw = 0; sw < BN / 32; ++sw) {
        const int r = sw * 32 + (tid >> 3);
        const int c8 = (tid & 7) ^ (r & 7);
        gload_lds16(Bb + (size_t)r * p.ldb + c8 * 8, Bs + (sw * 256 + tid) * 16);
      }
    }
    __syncthreads();
    // ---- compute: 2 x K=32 MFMA sub-steps ----
#pragma unroll
    for (int kk = 0; kk < 2; ++kk) {
      const int kb = kk * 64 + (lane >> 4) * 16;  // byte offset of k in row
      short8 aF[AM], bF[AN];
#pragma unroll
      for (int m = 0; m < AM; ++m) {
        const int r = wm * (16 * AM) + m * 16 + (lane & 15);
        aF[m] = *(const short8*)(As + ((r * 128 + kb) ^ ((r & 7) << 4)));
      }
#pragma unroll
      for (int n = 0; n < AN; ++n) {
        const int r = wn * (16 * AN) + n * 16 + (lane & 15);
        bF[n] = *(const short8*)(Bs + ((r * 128 + kb) ^ ((r & 7) << 4)));
      }
#pragma unroll
      for (int m = 0; m < AM; ++m)
#pragma unroll
        for (int n = 0; n < AN; ++n)
          acc[m][n] = __builtin_amdgcn_mfma_f32_16x16x32_bf16(
              aF[m], bF[n], acc[m][n], 0, 0, 0);
    }
    __syncthreads();
  }

  // ---- epilogue: C/D layout col=lane&15, row=(lane>>4)*4+j (m89/m91) ----
#pragma unroll
  for (int m = 0; m < AM; ++m) {
#pragma unroll
    for (int n = 0; n < AN; ++n) {
#pragma unroll
      for (int j = 0; j < 4; ++j) {
        const int gm = bm0 + wm * (16 * AM) + m * 16 + ((lane >> 4) << 2) + j;
        const int gn = bn0 + wn * (16 * AN) + n * 16 + (lane & 15);
        const float v = acc[m][n][j];
        if constexpr (MODE == M_PROJ) {
          const float vb = v + bias[gn];
          const int b = gm >> 11, s = gm & 2047;
          const int h = gn >> 6, d = gn & 63;
          short* C = (short*)p.C;
          if (z < 2) {  // q,k: [b,h,s,d]
            C[(size_t)z * 4194304 + (((size_t)(b * 16 + h) * 2048 + s) * 64 + d)] = f2bf(vb);
          } else {      // v transposed: [b,h,d,s]
            C[(size_t)2 * 4194304 + (((size_t)(b * 16 + h) * 64 + d) * 2048 + s)] = f2bf(vb);
          }
        } else if constexpr (MODE == M_SCORES) {
          ((float*)p.C)[(size_t)z * 4194304 + (size_t)gm * 2048 + gn] = v * 0.125f;
        } else if constexpr (MODE == M_PV) {
          const int b = z >> 4, h = z & 15;  // ctx: [b,s, h*64+d] bf16
          ((short*)p.C)[((size_t)(b * 2048 + gm)) * 1024 + h * 64 + gn] = f2bf(v);
        } else {  // M_OUT
          ((float*)p.C)[(size_t)gm * 1024 + gn] = v + bias[gn];
        }
      }
    }
  }
}

// In-place row softmax over attn rows of 2048 floats; one block per row.
__global__ __launch_bounds__(256) void softmax_rows(float* __restrict__ attn) {
  float* p = attn + (size_t)blockIdx.x * 2048;
  const int t = threadIdx.x;
  float4 v0 = ((const float4*)p)[t];
  float4 v1 = ((const float4*)p)[t + 256];
  float m = fmaxf(fmaxf(fmaxf(v0.x, v0.y), fmaxf(v0.z, v0.w)),
                  fmaxf(fmaxf(v1.x, v1.y), fmaxf(v1.z, v1.w)));
#pragma unroll
  for (int off = 32; off > 0; off >>= 1) m = fmaxf(m, __shfl_xor(m, off, 64));
  __shared__ float red[8];
  if ((t & 63) == 0) red[t >> 6] = m;
  __syncthreads();
  m = fmaxf(fmaxf(red[0], red[1]), fmaxf(red[2], red[3]));
  v0.x = __expf(v0.x - m); v0.y = __expf(v0.y - m);
  v0.z = __expf(v0.z - m); v0.w = __expf(v0.w - m);
  v1.x = __expf(v1.x - m); v1.y = __expf(v1.y - m);
  v1.z = __expf(v1.z - m); v1.w = __expf(v1.w - m);
  float s = v0.x + v0.y + v0.z + v0.w + v1.x + v1.y + v1.z + v1.w;
#pragma unroll
  for (int off = 32; off > 0; off >>= 1) s += __shfl_xor(s, off, 64);
  if ((t & 63) == 0) red[4 + (t >> 6)] = s;
  __syncthreads();
  const float inv = 1.0f / (red[4] + red[5] + red[6] + red[7]);
  v0.x *= inv; v0.y *= inv; v0.z *= inv; v0.w *= inv;
  v1.x *= inv; v1.y *= inv; v1.z *= inv; v1.w *= inv;
  ((float4*)p)[t] = v0;
  ((float4*)p)[t + 256] = v1;
}

// Convert 4 weight matrices (1024x1024 f32) to bf16 in ws.
__global__ __launch_bounds__(256) void cvt_w(const float* w0, const float* w1,
                                             const float* w2, const float* w3,
                                             short* out) {
  const float* w = (blockIdx.y == 0) ? w0 : (blockIdx.y == 1) ? w1
                 : (blockIdx.y == 2) ? w2 : w3;
  short* o = out + (size_t)blockIdx.y * 1048576;
  const int i = (blockIdx.x * 256 + threadIdx.x) * 4;
  const float4 v = *(const float4*)(w + i);
  short4v s;
  s[0] = f2bf(v.x); s[1] = f2bf(v.y); s[2] = f2bf(v.z); s[3] = f2bf(v.w);
  *(short4v*)(o + i) = s;
}

extern "C" void kernel_launch(void* const* d_in, const int* in_sizes, int n_in,
                              void* d_out, int out_size, void* d_ws, size_t ws_size,
                              hipStream_t stream) {
  const float* query = (const float*)d_in[0];
  const float* key_  = (const float*)d_in[1];
  const float* value = (const float*)d_in[2];
  const float* Wq = (const float*)d_in[3];
  const float* bq = (const float*)d_in[4];
  const float* Wk = (const float*)d_in[5];
  const float* bk = (const float*)d_in[6];
  const float* Wv = (const float*)d_in[7];
  const float* bv = (const float*)d_in[8];
  const float* Wo = (const float*)d_in[9];
  const float* bo = (const float*)d_in[10];

  float* out  = (float*)d_out;
  float* attn = (float*)d_out + 4194304;

  short* ws   = (short*)d_ws;
  short* Wb   = ws;                       // 4 x 1048576 bf16
  short* qkv  = ws + 4194304;             // q, k, vT: 3 x 4194304 bf16
  short* ctx  = ws + 4 * 4194304;         // 4194304 bf16

  // 1. weights -> bf16
  cvt_w<<<dim3(1024, 4), 256, 0, stream>>>(Wq, Wk, Wv, Wo, Wb);

  // 2. QKV projections (z=0:q, 1:k, 2:vT), M=4096 N=1024 K=1024
  {
    GP p{};
    p.A0 = query; p.A1 = key_; p.A2 = value;
    p.B = Wb; p.b0 = bq; p.b1 = bk; p.b2 = bv;
    p.C = qkv;
    p.lda = 1024; p.ldb = 1024; p.K = 1024;
    p.aBS = 0; p.bBS = 1048576;
    gemm_nt<2, 2, 4, 4, true, M_PROJ><<<dim3(8, 32, 3), 256, 0, stream>>>(p);
  }
  // 3. scores = q k^T * 0.125 per head, M=N=2048 K=64, z = b*16+h
  {
    GP p{};
    p.A0 = qkv;
    p.B = qkv + 4194304;
    p.C = attn;
    p.lda = 64; p.ldb = 64; p.K = 64;
    p.aBS = 131072; p.bBS = 131072;
    gemm_nt<2, 2, 4, 4, false, M_SCORES><<<dim3(16, 16, 32), 256, 0, stream>>>(p);
  }
  // 4. softmax rows in place (65536 rows)
  softmax_rows<<<dim3(65536), 256, 0, stream>>>(attn);
  // 5. ctx = attn @ v  (NT vs vT), M=2048 N=64 K=2048 per head
  {
    GP p{};
    p.A0 = attn;
    p.B = qkv + 2 * 4194304;
    p.C = ctx;
    p.lda = 2048; p.ldb = 2048; p.K = 2048;
    p.aBS = 4194304; p.bBS = 131072;
    gemm_nt<2, 2, 4, 2, true, M_PV><<<dim3(1, 16, 32), 256, 0, stream>>>(p);
  }
  // 6. out = ctx @ Wo^T + bo, M=4096 N=1024 K=1024
  {
    GP p{};
    p.A0 = ctx;
    p.B = Wb + 3 * 1048576;
    p.b0 = bo;
    p.C = out;
    p.lda = 1024; p.ldb = 1024; p.K = 1024;
    p.aBS = 0; p.bBS = 0;
    gemm_nt<2, 2, 4, 4, false, M_OUT><<<dim3(8, 32, 1), 256, 0, stream>>>(p);
  }
}

// Round 2
// 365.943 us; speedup vs baseline: 1.7929x; 1.7929x over previous
//
#include <hip/hip_runtime.h>
#include <stdint.h>

// MultiHeadAttention fwd. Round 2: fused two-pass flash attention.
// d_out = [out: 4194304 f32][attn: 134217728 f32]
// d_ws  = [W bf16: 4x1M][q bf16][k bf16][vT bf16][ctx bf16]  (40 MB)
// q is pre-scaled by 0.125 at projection (exact pow2).

#define DEV __device__ __forceinline__

typedef __attribute__((ext_vector_type(8))) short short8;
typedef __attribute__((ext_vector_type(4))) short short4v;
typedef __attribute__((ext_vector_type(4))) float f32x4;

DEV short f2bf(float f) {  // round-to-nearest-even f32 -> bf16 bits
  uint32_t u = __builtin_bit_cast(uint32_t, f);
  u += 0x7fffu + ((u >> 16) & 1u);
  return (short)(u >> 16);
}

DEV void gload_lds16(const void* g, void* l) {
  __builtin_amdgcn_global_load_lds(
      (const __attribute__((address_space(1))) void*)g,
      (__attribute__((address_space(3))) void*)l,
      16, 0, 0);
}

// Stage a tile of rows x (SPR*8) bf16 into LDS, linear dest, source
// pre-swizzled so that reads with byte^((row&7)<<4) see row-major data.
template<int UNITS, int SPR>
DEV void stage_swz(const short* src, int stride, char* lds, int tid) {
#pragma unroll
  for (int i = 0; i < UNITS; ++i) {
    const int u = tid + i * 256;
    const int r = u / SPR;
    const int s = (u % SPR) ^ (r & 7);
    gload_lds16(src + (size_t)r * stride + s * 8, lds + u * 16);
  }
}

DEV short8 ldsfrag(const char* lds, int row, int kbyte, int rowb) {
  return *(const short8*)(lds + row * rowb + (kbyte ^ ((row & 7) << 4)));
}

// ---------------------------------------------------------------------------
// Fused attention: per (head z, q-block of 128 rows):
//  pass1: online row max/sum over 16 K-tiles of 128.
//  pass2: recompute S, P=exp(S-m)/l -> write attn f32, PV via per-wave LDS.
// ---------------------------------------------------------------------------
__global__ __launch_bounds__(256) void attn_fused(
    const short* __restrict__ q, const short* __restrict__ k,
    const short* __restrict__ vT, float* __restrict__ attn,
    short* __restrict__ ctx) {
  __shared__ __align__(16) char Qs[128 * 128];
  __shared__ __align__(16) char Ks[128 * 128];
  __shared__ __align__(16) char Vs[64 * 256];
  __shared__ __align__(16) char Ps[4 * 32 * 128];  // per-wave 32x32 f32

  const int tid = threadIdx.x;
  const int lane = tid & 63;
  const int wm = tid >> 6;        // wave owns q-rows [wm*32, wm*32+32)
  const int c = lane & 15;
  const int g = lane >> 4;
  const int z = blockIdx.y;       // b*16+h
  const int qb = blockIdx.x;

  const short* qz = q + (size_t)z * 131072 + (size_t)qb * 128 * 64;
  const short* kz = k + (size_t)z * 131072;
  const short* vz = vT + (size_t)z * 131072;
  float* az = attn + (size_t)z * 4194304 + (size_t)qb * 128 * 2048;

  stage_swz<4, 8>(qz, 64, Qs, tid);

  float m_run[2][4], l_run[2][4];
#pragma unroll
  for (int m = 0; m < 2; ++m)
#pragma unroll
    for (int j = 0; j < 4; ++j) { m_run[m][j] = -1e30f; l_run[m][j] = 0.f; }

  short8 qf[2][2];

  // ---------------- pass 1: row max / sum ----------------
  for (int kt = 0; kt < 16; ++kt) {
    __syncthreads();
    stage_swz<4, 8>(kz + kt * 8192, 64, Ks, tid);
    __syncthreads();
    if (kt == 0) {
#pragma unroll
      for (int m = 0; m < 2; ++m)
#pragma unroll
        for (int kk = 0; kk < 2; ++kk)
          qf[m][kk] = ldsfrag(Qs, wm * 32 + m * 16 + c, kk * 64 + g * 16, 128);
    }
    f32x4 s[2][8];
#pragma unroll
    for (int m = 0; m < 2; ++m)
#pragma unroll
      for (int n = 0; n < 8; ++n) s[m][n] = f32x4{0.f, 0.f, 0.f, 0.f};
#pragma unroll
    for (int kk = 0; kk < 2; ++kk) {
#pragma unroll
      for (int n = 0; n < 8; ++n) {
        const short8 bf = ldsfrag(Ks, n * 16 + c, kk * 64 + g * 16, 128);
#pragma unroll
        for (int m = 0; m < 2; ++m)
          s[m][n] = __builtin_amdgcn_mfma_f32_16x16x32_bf16(
              qf[m][kk], bf, s[m][n], 0, 0, 0);
      }
    }
#pragma unroll
    for (int m = 0; m < 2; ++m) {
#pragma unroll
      for (int j = 0; j < 4; ++j) {
        float tm = s[m][0][j];
#pragma unroll
        for (int n = 1; n < 8; ++n) tm = fmaxf(tm, s[m][n][j]);
        tm = fmaxf(tm, __shfl_xor(tm, 1, 64));
        tm = fmaxf(tm, __shfl_xor(tm, 2, 64));
        tm = fmaxf(tm, __shfl_xor(tm, 4, 64));
        tm = fmaxf(tm, __shfl_xor(tm, 8, 64));
        const float nm = fmaxf(m_run[m][j], tm);
        float sum = 0.f;
#pragma unroll
        for (int n = 0; n < 8; ++n) sum += __expf(s[m][n][j] - nm);
        sum += __shfl_xor(sum, 1, 64);
        sum += __shfl_xor(sum, 2, 64);
        sum += __shfl_xor(sum, 4, 64);
        sum += __shfl_xor(sum, 8, 64);
        l_run[m][j] = l_run[m][j] * __expf(m_run[m][j] - nm) + sum;
        m_run[m][j] = nm;
      }
    }
  }

  float inv_l[2][4];
#pragma unroll
  for (int m = 0; m < 2; ++m)
#pragma unroll
    for (int j = 0; j < 4; ++j) inv_l[m][j] = 1.0f / l_run[m][j];

  f32x4 o[2][4];
#pragma unroll
  for (int m = 0; m < 2; ++m)
#pragma unroll
    for (int n = 0; n < 4; ++n) o[m][n] = f32x4{0.f, 0.f, 0.f, 0.f};

  char* Pw = Ps + wm * 4096;  // wave-private 32 rows x 128B

  // ---------------- pass 2: P write + PV ----------------
  for (int kt = 0; kt < 16; ++kt) {
    __syncthreads();
    stage_swz<4, 8>(kz + kt * 8192, 64, Ks, tid);
    stage_swz<4, 16>(vz + kt * 128, 2048, Vs, tid);
    __syncthreads();
    f32x4 s[2][8];
#pragma unroll
    for (int m = 0; m < 2; ++m)
#pragma unroll
      for (int n = 0; n < 8; ++n) s[m][n] = f32x4{0.f, 0.f, 0.f, 0.f};
#pragma unroll
    for (int kk = 0; kk < 2; ++kk) {
#pragma unroll
      for (int n = 0; n < 8; ++n) {
        const short8 bf = ldsfrag(Ks, n * 16 + c, kk * 64 + g * 16, 128);
#pragma unroll
        for (int m = 0; m < 2; ++m)
          s[m][n] = __builtin_amdgcn_mfma_f32_16x16x32_bf16(
              qf[m][kk], bf, s[m][n], 0, 0, 0);
      }
    }
    // P = exp(s - m)/l; write attn f32
#pragma unroll
    for (int m = 0; m < 2; ++m) {
#pragma unroll
      for (int j = 0; j < 4; ++j) {
        const float mm = m_run[m][j], il = inv_l[m][j];
#pragma unroll
        for (int n = 0; n < 8; ++n) s[m][n][j] = __expf(s[m][n][j] - mm) * il;
      }
    }
#pragma unroll
    for (int m = 0; m < 2; ++m)
#pragma unroll
      for (int n = 0; n < 8; ++n)
#pragma unroll
        for (int j = 0; j < 4; ++j)
          az[(size_t)(wm * 32 + m * 16 + g * 4 + j) * 2048 + kt * 128 +
             n * 16 + c] = s[m][n][j];
    // PV in 4 chunks of k'=32 through wave-private LDS (no barriers needed)
#pragma unroll
    for (int kc = 0; kc < 4; ++kc) {
#pragma unroll
      for (int m = 0; m < 2; ++m)
#pragma unroll
        for (int nn = 0; nn < 2; ++nn)
#pragma unroll
          for (int j = 0; j < 4; ++j) {
            const int r = m * 16 + g * 4 + j;
            *(float*)(Pw + r * 128 +
                      ((((nn * 16 + c) * 4)) ^ ((r & 7) << 4))) =
                s[m][kc * 2 + nn][j];
          }
      short8 paf[2];
#pragma unroll
      for (int m = 0; m < 2; ++m) {
        const int r = m * 16 + c;
        const int X = (r & 7) << 4;
        const f32x4 lo = *(const f32x4*)(Pw + r * 128 + ((g * 32) ^ X));
        const f32x4 hi = *(const f32x4*)(Pw + r * 128 + ((g * 32 + 16) ^ X));
        short8 af;
#pragma unroll
        for (int e = 0; e < 4; ++e) { af[e] = f2bf(lo[e]); af[4 + e] = f2bf(hi[e]); }
        paf[m] = af;
      }
#pragma unroll
      for (int n2 = 0; n2 < 4; ++n2) {
        const short8 bf = ldsfrag(Vs, n2 * 16 + c, kc * 64 + g * 16, 256);
#pragma unroll
        for (int m = 0; m < 2; ++m)
          o[m][n2] = __builtin_amdgcn_mfma_f32_16x16x32_bf16(
              paf[m], bf, o[m][n2], 0, 0, 0);
      }
    }
  }

  // epilogue: ctx[b, s, h*64+d] bf16
  const int b = z >> 4, h = z & 15;
#pragma unroll
  for (int m = 0; m < 2; ++m)
#pragma unroll
    for (int n2 = 0; n2 < 4; ++n2)
#pragma unroll
      for (int j = 0; j < 4; ++j)
        ctx[((size_t)(b * 2048 + qb * 128 + wm * 32 + m * 16 + g * 4 + j)) *
                1024 + h * 64 + n2 * 16 + c] = f2bf(o[m][n2][j]);
}

// ---------------------------------------------------------------------------
// NT bf16 GEMM (projections). C[m,n] = sum_k A[m,k]*B[n,k].
// ---------------------------------------------------------------------------
enum { M_PROJ = 0, M_OUT = 3 };

struct GP {
  const void* A0; const void* A1; const void* A2;
  const short* B;
  const float* b0; const float* b1; const float* b2;
  void* C;
  int lda, ldb, K;
  long aBS, bBS;
};

template<int WM, int WN, int AM, int AN, bool CONVA, int MODE>
__global__ __launch_bounds__(256) void gemm_nt(GP p) {
  constexpr int BM = WM * 16 * AM;
  constexpr int BN = WN * 16 * AN;
  static_assert(WM * WN == 4, "4 waves / 256 threads");
  __shared__ __align__(16) char As[BM * 128];
  __shared__ __align__(16) char Bs[BN * 128];

  const int tid = threadIdx.x;
  const int lane = tid & 63;
  const int z = blockIdx.z;
  const int bm0 = blockIdx.y * BM;
  const int bn0 = blockIdx.x * BN;

  const void* Aroot; const float* bias;
  if constexpr (MODE == M_PROJ) {
    Aroot = (z == 0) ? p.A0 : (z == 1 ? p.A1 : p.A2);
    bias  = (z == 0) ? p.b0 : (z == 1 ? p.b1 : p.b2);
  } else {
    Aroot = p.A0; bias = p.b0;
  }

  f32x4 acc[AM][AN];
#pragma unroll
  for (int m = 0; m < AM; ++m)
#pragma unroll
    for (int n = 0; n < AN; ++n) acc[m][n] = f32x4{0.f, 0.f, 0.f, 0.f};

  const int wave = tid >> 6;
  const int wm = wave / WN;
  const int wn = wave % WN;

  const int nK = p.K >> 6;
  for (int kt = 0; kt < nK; ++kt) {
    if constexpr (CONVA) {
      const float* Af = (const float*)Aroot + (size_t)z * p.aBS +
                        (size_t)bm0 * p.lda + kt * 64;
#pragma unroll
      for (int sw = 0; sw < BM / 16; ++sw) {
        const int r = sw * 16 + (tid >> 4);
        const int s8 = tid & 15;
        const float4 v = *(const float4*)(Af + (size_t)r * p.lda + s8 * 4);
        short4v oo;
        oo[0] = f2bf(v.x); oo[1] = f2bf(v.y); oo[2] = f2bf(v.z); oo[3] = f2bf(v.w);
        const int boff = (r * 128 + s8 * 8) ^ ((r & 7) << 4);
        *(short4v*)(As + boff) = oo;
      }
    } else {
      const short* Ab = (const short*)Aroot + (size_t)z * p.aBS +
                        (size_t)bm0 * p.lda + kt * 64;
#pragma unroll
      for (int sw = 0; sw < BM / 32; ++sw) {
        const int r = sw * 32 + (tid >> 3);
        const int c8 = (tid & 7) ^ (r & 7);
        gload_lds16(Ab + (size_t)r * p.lda + c8 * 8, As + (sw * 256 + tid) * 16);
      }
    }
    {
      const short* Bb = p.B + (size_t)z * p.bBS + (size_t)bn0 * p.ldb + kt * 64;
#pragma unroll
      for (int sw = 0; sw < BN / 32; ++sw) {
        const int r = sw * 32 + (tid >> 3);
        const int c8 = (tid & 7) ^ (r & 7);
        gload_lds16(Bb + (size_t)r * p.ldb + c8 * 8, Bs + (sw * 256 + tid) * 16);
      }
    }
    __syncthreads();
#pragma unroll
    for (int kk = 0; kk < 2; ++kk) {
      const int kb = kk * 64 + (lane >> 4) * 16;
      short8 aF[AM], bF[AN];
#pragma unroll
      for (int m = 0; m < AM; ++m) {
        const int r = wm * (16 * AM) + m * 16 + (lane & 15);
        aF[m] = *(const short8*)(As + ((r * 128 + kb) ^ ((r & 7) << 4)));
      }
#pragma unroll
      for (int n = 0; n < AN; ++n) {
        const int r = wn * (16 * AN) + n * 16 + (lane & 15);
        bF[n] = *(const short8*)(Bs + ((r * 128 + kb) ^ ((r & 7) << 4)));
      }
#pragma unroll
      for (int m = 0; m < AM; ++m)
#pragma unroll
        for (int n = 0; n < AN; ++n)
          acc[m][n] = __builtin_amdgcn_mfma_f32_16x16x32_bf16(
              aF[m], bF[n], acc[m][n], 0, 0, 0);
    }
    __syncthreads();
  }

#pragma unroll
  for (int m = 0; m < AM; ++m) {
#pragma unroll
    for (int n = 0; n < AN; ++n) {
#pragma unroll
      for (int j = 0; j < 4; ++j) {
        const int gm = bm0 + wm * (16 * AM) + m * 16 + ((lane >> 4) << 2) + j;
        const int gn = bn0 + wn * (16 * AN) + n * 16 + (lane & 15);
        const float v = acc[m][n][j];
        if constexpr (MODE == M_PROJ) {
          float vb = v + bias[gn];
          if (z == 0) vb *= 0.125f;  // fold 1/sqrt(depth) into q (exact pow2)
          const int b = gm >> 11, s = gm & 2047;
          const int h = gn >> 6, d = gn & 63;
          short* C = (short*)p.C;
          if (z < 2) {  // q,k: [b,h,s,d]
            C[(size_t)z * 4194304 + (((size_t)(b * 16 + h) * 2048 + s) * 64 + d)] = f2bf(vb);
          } else {      // v transposed: [b,h,d,s]
            C[(size_t)2 * 4194304 + (((size_t)(b * 16 + h) * 64 + d) * 2048 + s)] = f2bf(vb);
          }
        } else {  // M_OUT
          ((float*)p.C)[(size_t)gm * 1024 + gn] = v + bias[gn];
        }
      }
    }
  }
}

// Convert 4 weight matrices (1024x1024 f32) to bf16 in ws.
__global__ __launch_bounds__(256) void cvt_w(const float* w0, const float* w1,
                                             const float* w2, const float* w3,
                                             short* out) {
  const float* w = (blockIdx.y == 0) ? w0 : (blockIdx.y == 1) ? w1
                 : (blockIdx.y == 2) ? w2 : w3;
  short* o = out + (size_t)blockIdx.y * 1048576;
  const int i = (blockIdx.x * 256 + threadIdx.x) * 4;
  const float4 v = *(const float4*)(w + i);
  short4v s;
  s[0] = f2bf(v.x); s[1] = f2bf(v.y); s[2] = f2bf(v.z); s[3] = f2bf(v.w);
  *(short4v*)(o + i) = s;
}

extern "C" void kernel_launch(void* const* d_in, const int* in_sizes, int n_in,
                              void* d_out, int out_size, void* d_ws, size_t ws_size,
                              hipStream_t stream) {
  const float* query = (const float*)d_in[0];
  const float* key_  = (const float*)d_in[1];
  const float* value = (const float*)d_in[2];
  const float* Wq = (const float*)d_in[3];
  const float* bq = (const float*)d_in[4];
  const float* Wk = (const float*)d_in[5];
  const float* bk = (const float*)d_in[6];
  const float* Wv = (const float*)d_in[7];
  const float* bv = (const float*)d_in[8];
  const float* Wo = (const float*)d_in[9];
  const float* bo = (const float*)d_in[10];

  float* out  = (float*)d_out;
  float* attn = (float*)d_out + 4194304;

  short* ws   = (short*)d_ws;
  short* Wb   = ws;                       // 4 x 1048576 bf16
  short* qkv  = ws + 4194304;             // q, k, vT: 3 x 4194304 bf16
  short* ctx  = ws + 4 * 4194304;         // 4194304 bf16

  cvt_w<<<dim3(1024, 4), 256, 0, stream>>>(Wq, Wk, Wv, Wo, Wb);

  {  // QKV projections (z=0:q scaled, 1:k, 2:vT)
    GP p{};
    p.A0 = query; p.A1 = key_; p.A2 = value;
    p.B = Wb; p.b0 = bq; p.b1 = bk; p.b2 = bv;
    p.C = qkv;
    p.lda = 1024; p.ldb = 1024; p.K = 1024;
    p.aBS = 0; p.bBS = 1048576;
    gemm_nt<2, 2, 4, 4, true, M_PROJ><<<dim3(8, 32, 3), 256, 0, stream>>>(p);
  }

  // fused attention: scores+softmax+attn-write+PV
  attn_fused<<<dim3(16, 32), 256, 0, stream>>>(
      qkv, qkv + 4194304, qkv + 2 * 4194304, attn, ctx);

  {  // out = ctx @ Wo^T + bo
    GP p{};
    p.A0 = ctx;
    p.B = Wb + 3 * 1048576;
    p.b0 = bo;
    p.C = out;
    p.lda = 1024; p.ldb = 1024; p.K = 1024;
    p.aBS = 0; p.bBS = 0;
    gemm_nt<2, 2, 4, 4, false, M_OUT><<<dim3(8, 32, 1), 256, 0, stream>>>(p);
  }
}

// Round 3
// 315.627 us; speedup vs baseline: 2.0787x; 1.1594x over previous
//
#include <hip/hip_runtime.h>
#include <stdint.h>

// MultiHeadAttention fwd. Round 3: barrier-free fused attention with
// direct-from-L2 K/V fragment loads; XCD-swizzled projection GEMMs;
// nontemporal attn/out stores; no-max softmax (shift-invariant, C=0).
// d_out = [out: 4194304 f32][attn: 134217728 f32]
// d_ws  = [W bf16: 4x1M][q bf16][k bf16][vT bf16][ctx bf16]  (40 MB)
// q is pre-scaled by 0.125 at projection (exact pow2).

#define DEV __device__ __forceinline__

typedef __attribute__((ext_vector_type(8))) short short8;
typedef __attribute__((ext_vector_type(4))) short short4v;
typedef __attribute__((ext_vector_type(4))) float f32x4;
typedef __attribute__((ext_vector_type(4))) uint32_t u32x4;

DEV short f2bf(float f) {  // round-to-nearest-even f32 -> bf16 bits
  uint32_t u = __builtin_bit_cast(uint32_t, f);
  u += 0x7fffu + ((u >> 16) & 1u);
  return (short)(u >> 16);
}

DEV uint32_t cvtpk_bf16(float a, float b) {  // hi.bf16(b) | lo.bf16(a), RNE
  uint32_t r;
  asm("v_cvt_pk_bf16_f32 %0, %1, %2" : "=v"(r) : "v"(a), "v"(b));
  return r;
}

DEV void gload_lds16(const void* g, void* l) {
  __builtin_amdgcn_global_load_lds(
      (const __attribute__((address_space(1))) void*)g,
      (__attribute__((address_space(3))) void*)l,
      16, 0, 0);
}

// ---------------------------------------------------------------------------
// Fused attention, barrier-free. Per block (z = b*16+h, qb = 128-row block):
//  Q frags in regs; K,V fragments loaded directly from global (L2-resident).
//  pass1: l[row] = sum_k exp(s)   (no max; deferred cross-lane reduce)
//  pass2: recompute s, P = exp(s)*inv_l -> attn (nontemporal), PV via
//         wave-private LDS bounce (no __syncthreads anywhere).
// ---------------------------------------------------------------------------
__global__ __launch_bounds__(256) void attn_fused(
    const short* __restrict__ q, const short* __restrict__ k,
    const short* __restrict__ vT, float* __restrict__ attn,
    short* __restrict__ ctx) {
  __shared__ __align__(16) char Ps[4 * 32 * 128];  // per-wave 32x32 f32

  const int tid = threadIdx.x;
  const int lane = tid & 63;
  const int wm = tid >> 6;      // wave owns q-rows [wm*32, wm*32+32)
  const int c = lane & 15;
  const int g = lane >> 4;
  // XCD chunk swizzle (512 blocks, 64 per XCD -> 4 heads per XCD L2)
  const int orig = blockIdx.x;
  const int sid = (orig & 7) * 64 + (orig >> 3);
  const int qb = sid & 15;
  const int z = sid >> 4;       // b*16+h

  const short* qz = q + (size_t)z * 131072 + (size_t)(qb * 128 + wm * 32) * 64;
  const short* kz = k + (size_t)z * 131072;
  const short* vz = vT + (size_t)z * 131072;
  float* az = attn + (size_t)z * 4194304 + (size_t)(qb * 128 + wm * 32) * 2048;

  // Q fragments (rows m*16+c, k-chunk kk*32+g*8)
  short8 qf[2][2];
#pragma unroll
  for (int m = 0; m < 2; ++m)
#pragma unroll
    for (int kk = 0; kk < 2; ++kk)
      qf[m][kk] = *(const short8*)(qz + (m * 16 + c) * 64 + kk * 32 + g * 8);

  // ---------------- pass 1: row sums of exp(s) ----------------
  float l_part[2][4];
#pragma unroll
  for (int m = 0; m < 2; ++m)
#pragma unroll
    for (int j = 0; j < 4; ++j) l_part[m][j] = 0.f;

  for (int kt = 0; kt < 16; ++kt) {
    const short* kzt = kz + kt * 8192;
    f32x4 s[2][8];
#pragma unroll
    for (int m = 0; m < 2; ++m)
#pragma unroll
      for (int n = 0; n < 8; ++n) s[m][n] = f32x4{0.f, 0.f, 0.f, 0.f};
#pragma unroll
    for (int kk = 0; kk < 2; ++kk) {
#pragma unroll
      for (int n = 0; n < 8; ++n) {
        const short8 bf =
            *(const short8*)(kzt + (n * 16 + c) * 64 + kk * 32 + g * 8);
        s[0][n] = __builtin_amdgcn_mfma_f32_16x16x32_bf16(qf[0][kk], bf,
                                                          s[0][n], 0, 0, 0);
        s[1][n] = __builtin_amdgcn_mfma_f32_16x16x32_bf16(qf[1][kk], bf,
                                                          s[1][n], 0, 0, 0);
      }
    }
#pragma unroll
    for (int m = 0; m < 2; ++m)
#pragma unroll
      for (int j = 0; j < 4; ++j)
#pragma unroll
        for (int n = 0; n < 8; ++n) l_part[m][j] += __expf(s[m][n][j]);
  }

  float inv_l[2][4];
#pragma unroll
  for (int m = 0; m < 2; ++m)
#pragma unroll
    for (int j = 0; j < 4; ++j) {
      float l = l_part[m][j];
      l += __shfl_xor(l, 1, 64);
      l += __shfl_xor(l, 2, 64);
      l += __shfl_xor(l, 4, 64);
      l += __shfl_xor(l, 8, 64);
      inv_l[m][j] = 1.0f / l;
    }

  // ---------------- pass 2: attn write + PV ----------------
  f32x4 o[2][4];
#pragma unroll
  for (int m = 0; m < 2; ++m)
#pragma unroll
    for (int n = 0; n < 4; ++n) o[m][n] = f32x4{0.f, 0.f, 0.f, 0.f};

  char* Pw = Ps + wm * 4096;  // wave-private 32 rows x 128B, never barriered

  for (int kt = 0; kt < 16; ++kt) {
    const short* kzt = kz + kt * 8192;
    f32x4 s[2][8];
#pragma unroll
    for (int m = 0; m < 2; ++m)
#pragma unroll
      for (int n = 0; n < 8; ++n) s[m][n] = f32x4{0.f, 0.f, 0.f, 0.f};
#pragma unroll
    for (int kk = 0; kk < 2; ++kk) {
#pragma unroll
      for (int n = 0; n < 8; ++n) {
        const short8 bf =
            *(const short8*)(kzt + (n * 16 + c) * 64 + kk * 32 + g * 8);
        s[0][n] = __builtin_amdgcn_mfma_f32_16x16x32_bf16(qf[0][kk], bf,
                                                          s[0][n], 0, 0, 0);
        s[1][n] = __builtin_amdgcn_mfma_f32_16x16x32_bf16(qf[1][kk], bf,
                                                          s[1][n], 0, 0, 0);
      }
    }
    // P = exp(s) * inv_l, streamed to attn (nontemporal: keep K/V in L2)
#pragma unroll
    for (int m = 0; m < 2; ++m)
#pragma unroll
      for (int j = 0; j < 4; ++j) {
        const float il = inv_l[m][j];
#pragma unroll
        for (int n = 0; n < 8; ++n) s[m][n][j] = __expf(s[m][n][j]) * il;
      }
#pragma unroll
    for (int m = 0; m < 2; ++m)
#pragma unroll
      for (int n = 0; n < 8; ++n)
#pragma unroll
        for (int j = 0; j < 4; ++j)
          __builtin_nontemporal_store(
              s[m][n][j], az + (size_t)(m * 16 + g * 4 + j) * 2048 +
                              kt * 128 + n * 16 + c);
    // PV: 4 chunks of k'=32 through wave-private LDS transpose bounce
#pragma unroll
    for (int kc = 0; kc < 4; ++kc) {
#pragma unroll
      for (int m = 0; m < 2; ++m)
#pragma unroll
        for (int nn = 0; nn < 2; ++nn)
#pragma unroll
          for (int j = 0; j < 4; ++j) {
            const int r = m * 16 + g * 4 + j;
            *(float*)(Pw + r * 128 +
                      (((nn * 16 + c) * 4) ^ ((r & 7) << 4))) =
                s[m][kc * 2 + nn][j];
          }
      short8 paf[2];
#pragma unroll
      for (int m = 0; m < 2; ++m) {
        const int r = m * 16 + c;
        const int X = (r & 7) << 4;
        const f32x4 lo = *(const f32x4*)(Pw + r * 128 + ((g * 32) ^ X));
        const f32x4 hi = *(const f32x4*)(Pw + r * 128 + ((g * 32 + 16) ^ X));
        u32x4 pk;
        pk[0] = cvtpk_bf16(lo[0], lo[1]);
        pk[1] = cvtpk_bf16(lo[2], lo[3]);
        pk[2] = cvtpk_bf16(hi[0], hi[1]);
        pk[3] = cvtpk_bf16(hi[2], hi[3]);
        paf[m] = __builtin_bit_cast(short8, pk);
      }
#pragma unroll
      for (int n2 = 0; n2 < 4; ++n2) {
        const short8 vf = *(const short8*)(vz + (size_t)(n2 * 16 + c) * 2048 +
                                           kt * 128 + kc * 32 + g * 8);
        o[0][n2] = __builtin_amdgcn_mfma_f32_16x16x32_bf16(paf[0], vf,
                                                           o[0][n2], 0, 0, 0);
        o[1][n2] = __builtin_amdgcn_mfma_f32_16x16x32_bf16(paf[1], vf,
                                                           o[1][n2], 0, 0, 0);
      }
    }
  }

  // epilogue: ctx[b, s, h*64+d] bf16 (re-read by out-proj: normal stores)
  const int b = z >> 4, h = z & 15;
#pragma unroll
  for (int m = 0; m < 2; ++m)
#pragma unroll
    for (int n2 = 0; n2 < 4; ++n2)
#pragma unroll
      for (int j = 0; j < 4; ++j)
        ctx[((size_t)(b * 2048 + qb * 128 + wm * 32 + m * 16 + g * 4 + j)) *
                1024 + h * 64 + n2 * 16 + c] = f2bf(o[m][n2][j]);
}

// ---------------------------------------------------------------------------
// NT bf16 GEMM (projections). C[m,n] = sum_k A[m,k]*B[n,k].
// Grid: (256, z) 1D-swizzled: XCD chunking so the 8 bn-blocks of one
// A-panel share one XCD's L2 (A fetched ~once per XCD).
// ---------------------------------------------------------------------------
enum { M_PROJ = 0, M_OUT = 3 };

struct GP {
  const void* A0; const void* A1; const void* A2;
  const short* B;
  const float* b0; const float* b1; const float* b2;
  void* C;
  int lda, ldb, K;
  long aBS, bBS;
};

template<int WM, int WN, int AM, int AN, bool CONVA, int MODE>
__global__ __launch_bounds__(256) void gemm_nt(GP p) {
  constexpr int BM = WM * 16 * AM;
  constexpr int BN = WN * 16 * AN;
  static_assert(WM * WN == 4, "4 waves / 256 threads");
  __shared__ __align__(16) char As[BM * 128];
  __shared__ __align__(16) char Bs[BN * 128];

  const int tid = threadIdx.x;
  const int lane = tid & 63;
  const int z = blockIdx.y;
  // bijective XCD chunk swizzle over 256 blocks (M/BM=32 x N/BN=8)
  const int orig = blockIdx.x;
  const int sid = (orig & 7) * 32 + (orig >> 3);
  const int bm0 = (sid >> 3) * BM;
  const int bn0 = (sid & 7) * BN;

  const void* Aroot; const float* bias;
  if constexpr (MODE == M_PROJ) {
    Aroot = (z == 0) ? p.A0 : (z == 1 ? p.A1 : p.A2);
    bias  = (z == 0) ? p.b0 : (z == 1 ? p.b1 : p.b2);
  } else {
    Aroot = p.A0; bias = p.b0;
  }

  f32x4 acc[AM][AN];
#pragma unroll
  for (int m = 0; m < AM; ++m)
#pragma unroll
    for (int n = 0; n < AN; ++n) acc[m][n] = f32x4{0.f, 0.f, 0.f, 0.f};

  const int wave = tid >> 6;
  const int wm = wave / WN;
  const int wn = wave % WN;

  const int nK = p.K >> 6;
  for (int kt = 0; kt < nK; ++kt) {
    if constexpr (CONVA) {  // fp32 source: reg-stage + convert + swizzled write
      const float* Af = (const float*)Aroot + (size_t)z * p.aBS +
                        (size_t)bm0 * p.lda + kt * 64;
#pragma unroll
      for (int sw = 0; sw < BM / 16; ++sw) {
        const int r = sw * 16 + (tid >> 4);
        const int s8 = tid & 15;
        const float4 v = *(const float4*)(Af + (size_t)r * p.lda + s8 * 4);
        short4v oo;
        oo[0] = f2bf(v.x); oo[1] = f2bf(v.y); oo[2] = f2bf(v.z); oo[3] = f2bf(v.w);
        const int boff = (r * 128 + s8 * 8) ^ ((r & 7) << 4);
        *(short4v*)(As + boff) = oo;
      }
    } else {  // bf16 source: global_load_lds, linear dest + pre-swizzled src
      const short* Ab = (const short*)Aroot + (size_t)z * p.aBS +
                        (size_t)bm0 * p.lda + kt * 64;
#pragma unroll
      for (int sw = 0; sw < BM / 32; ++sw) {
        const int r = sw * 32 + (tid >> 3);
        const int c8 = (tid & 7) ^ (r & 7);
        gload_lds16(Ab + (size_t)r * p.lda + c8 * 8, As + (sw * 256 + tid) * 16);
      }
    }
    {
      const short* Bb = p.B + (size_t)z * p.bBS + (size_t)bn0 * p.ldb + kt * 64;
#pragma unroll
      for (int sw = 0; sw < BN / 32; ++sw) {
        const int r = sw * 32 + (tid >> 3);
        const int c8 = (tid & 7) ^ (r & 7);
        gload_lds16(Bb + (size_t)r * p.ldb + c8 * 8, Bs + (sw * 256 + tid) * 16);
      }
    }
    __syncthreads();
#pragma unroll
    for (int kk = 0; kk < 2; ++kk) {
      const int kb = kk * 64 + (lane >> 4) * 16;
      short8 aF[AM], bF[AN];
#pragma unroll
      for (int m = 0; m < AM; ++m) {
        const int r = wm * (16 * AM) + m * 16 + (lane & 15);
        aF[m] = *(const short8*)(As + ((r * 128 + kb) ^ ((r & 7) << 4)));
      }
#pragma unroll
      for (int n = 0; n < AN; ++n) {
        const int r = wn * (16 * AN) + n * 16 + (lane & 15);
        bF[n] = *(const short8*)(Bs + ((r * 128 + kb) ^ ((r & 7) << 4)));
      }
#pragma unroll
      for (int m = 0; m < AM; ++m)
#pragma unroll
        for (int n = 0; n < AN; ++n)
          acc[m][n] = __builtin_amdgcn_mfma_f32_16x16x32_bf16(
              aF[m], bF[n], acc[m][n], 0, 0, 0);
    }
    __syncthreads();
  }

#pragma unroll
  for (int m = 0; m < AM; ++m) {
#pragma unroll
    for (int n = 0; n < AN; ++n) {
#pragma unroll
      for (int j = 0; j < 4; ++j) {
        const int gm = bm0 + wm * (16 * AM) + m * 16 + ((lane >> 4) << 2) + j;
        const int gn = bn0 + wn * (16 * AN) + n * 16 + (lane & 15);
        const float v = acc[m][n][j];
        if constexpr (MODE == M_PROJ) {
          float vb = v + bias[gn];
          if (z == 0) vb *= 0.125f;  // fold 1/sqrt(depth) into q (exact pow2)
          const int b = gm >> 11, s = gm & 2047;
          const int h = gn >> 6, d = gn & 63;
          short* C = (short*)p.C;
          if (z < 2) {  // q,k: [b,h,s,d]
            C[(size_t)z * 4194304 + (((size_t)(b * 16 + h) * 2048 + s) * 64 + d)] = f2bf(vb);
          } else {      // v transposed: [b,h,d,s]
            C[(size_t)2 * 4194304 + (((size_t)(b * 16 + h) * 64 + d) * 2048 + s)] = f2bf(vb);
          }
        } else {  // M_OUT: never re-read -> nontemporal
          __builtin_nontemporal_store(
              v + bias[gn], (float*)p.C + (size_t)gm * 1024 + gn);
        }
      }
    }
  }
}

// Convert 4 weight matrices (1024x1024 f32) to bf16 in ws.
__global__ __launch_bounds__(256) void cvt_w(const float* w0, const float* w1,
                                             const float* w2, const float* w3,
                                             short* out) {
  const float* w = (blockIdx.y == 0) ? w0 : (blockIdx.y == 1) ? w1
                 : (blockIdx.y == 2) ? w2 : w3;
  short* o = out + (size_t)blockIdx.y * 1048576;
  const int i = (blockIdx.x * 256 + threadIdx.x) * 4;
  const float4 v = *(const float4*)(w + i);
  short4v s;
  s[0] = f2bf(v.x); s[1] = f2bf(v.y); s[2] = f2bf(v.z); s[3] = f2bf(v.w);
  *(short4v*)(o + i) = s;
}

extern "C" void kernel_launch(void* const* d_in, const int* in_sizes, int n_in,
                              void* d_out, int out_size, void* d_ws, size_t ws_size,
                              hipStream_t stream) {
  const float* query = (const float*)d_in[0];
  const float* key_  = (const float*)d_in[1];
  const float* value = (const float*)d_in[2];
  const float* Wq = (const float*)d_in[3];
  const float* bq = (const float*)d_in[4];
  const float* Wk = (const float*)d_in[5];
  const float* bk = (const float*)d_in[6];
  const float* Wv = (const float*)d_in[7];
  const float* bv = (const float*)d_in[8];
  const float* Wo = (const float*)d_in[9];
  const float* bo = (const float*)d_in[10];

  float* out  = (float*)d_out;
  float* attn = (float*)d_out + 4194304;

  short* ws   = (short*)d_ws;
  short* Wb   = ws;                       // 4 x 1048576 bf16
  short* qkv  = ws + 4194304;             // q, k, vT: 3 x 4194304 bf16
  short* ctx  = ws + 4 * 4194304;         // 4194304 bf16

  cvt_w<<<dim3(1024, 4), 256, 0, stream>>>(Wq, Wk, Wv, Wo, Wb);

  {  // QKV projections (z=0:q scaled, 1:k, 2:vT)
    GP p{};
    p.A0 = query; p.A1 = key_; p.A2 = value;
    p.B = Wb; p.b0 = bq; p.b1 = bk; p.b2 = bv;
    p.C = qkv;
    p.lda = 1024; p.ldb = 1024; p.K = 1024;
    p.aBS = 0; p.bBS = 1048576;
    gemm_nt<2, 2, 4, 4, true, M_PROJ><<<dim3(256, 3), 256, 0, stream>>>(p);
  }

  // fused attention: scores+softmax+attn-write+PV, barrier-free
  attn_fused<<<dim3(512), 256, 0, stream>>>(
      qkv, qkv + 4194304, qkv + 2 * 4194304, attn, ctx);

  {  // out = ctx @ Wo^T + bo
    GP p{};
    p.A0 = ctx;
    p.B = Wb + 3 * 1048576;
    p.b0 = bo;
    p.C = out;
    p.lda = 1024; p.ldb = 1024; p.K = 1024;
    p.aBS = 0; p.bBS = 0;
    gemm_nt<2, 2, 4, 4, false, M_OUT><<<dim3(256, 1), 256, 0, stream>>>(p);
  }
}